// Round 14
// baseline (531.726 us; speedup 1.0000x reference)
//
#include <hip/hip_runtime.h>
#include <hip/hip_bf16.h>

#define WIDTH 256
#define HW 65536
#define IMG 16777216   // 4*64*HW
#define NIMG 256
#define NSPLIT 16      // stats shards per image: cuts same-address atomic chains 16x (R9: 256-deep chains => 189us)

typedef __attribute__((ext_vector_type(8))) short bf8v;   // 8 bf16 = 4 VGPR (MFMA A/B frag)
typedef __attribute__((ext_vector_type(4))) float f4v;    // 4 f32 (MFMA C/D frag)

__device__ __forceinline__ float lrelu_f(float v){ return v > 0.f ? v : 0.01f*v; }
__device__ __forceinline__ unsigned short bf16u(float v){
    __hip_bfloat16 h = __float2bfloat16(v);
    return *(unsigned short*)&h;
}

// ---------------- stats finalize: ps (256 imgs x 16 splits x 2 sums) -> st (mean, inv_std) ----------------
__global__ __launch_bounds__(256) void k_statsf(const float* __restrict__ ps, float* __restrict__ st)
{
    const int img = threadIdx.x;
    const float* p = ps + blockIdx.x * (256 * NSPLIT * 2) + img * (NSPLIT * 2);
    float* o = st + blockIdx.x * 512;
    float S = 0.f, S2 = 0.f;
#pragma unroll
    for (int q = 0; q < NSPLIT; q++) { S += p[q * 2]; S2 += p[q * 2 + 1]; }
    const float m = S / 65536.f;
    const float var = S2 / 65536.f - m * m;
    o[img * 2]     = m;
    o[img * 2 + 1] = rsqrtf(var + 1e-5f);
}

// ---------------- attention MLP (single block; reads sharded raw sums, needs means only) ----------------
__global__ __launch_bounds__(256) void k_attention(const float* __restrict__ ps0,
    const float* __restrict__ wa1, const float* __restrict__ wa2, float* __restrict__ a2o)
{
    __shared__ float means[256];
    __shared__ float a1s[64];
    const int tid = threadIdx.x;
    {
        const float* p = ps0 + tid * (NSPLIT * 2);
        float S = 0.f;
#pragma unroll
        for (int q = 0; q < NSPLIT; q++) S += p[q * 2];
        means[tid] = S * (1.f / 65536.f);
    }
    __syncthreads();
    if (tid < 64) {
        const int b = tid >> 4, o = tid & 15;
        float s = 0.f;
        for (int c = 0; c < 64; c++) s += wa1[o * 64 + c] * means[b * 64 + c];
        a1s[b * 16 + o] = lrelu_f(s);
    }
    __syncthreads();
    {
        const int b = tid >> 6, c = tid & 63;
        float s = 0.f;
#pragma unroll
        for (int o = 0; o < 16; o++) s += wa2[c * 16 + o] * a1s[b * 16 + o];
        a2o[tid] = 1.f / (1.f + expf(-s));
    }
}

// ---------------- proj conv 3->64 3x3 + fused stats(st0) ----------------
// NOTE: cc loop must stay `#pragma unroll 2` — R7/R8 full-unrolled it; with the
// (256,3) VGPR cap (84) the ~90 hoisted loads spilled to scratch (552 MB WRITE).
__global__ __launch_bounds__(256, 3) void k_proj(const float* __restrict__ x,
    const float* __restrict__ wt, const float* __restrict__ bias,
    float* __restrict__ out, float* __restrict__ ps0)
{
    __shared__ float wl[3][9][32];
    const int tid = threadIdx.x;
    const int og = tid >> 5, xg = tid & 31;
    const int half = blockIdx.x & 1;
    const int y = (blockIdx.x >> 1) & 255;
    const int b = blockIdx.x >> 9;
    const int o_base = half * 32;
    const int o0l = og * 4;
    const int x0 = xg * 8;
    const int split = y & (NSPLIT - 1);

    for (int idx = tid; idx < 3 * 9 * 32; idx += 256) {
        const int o = idx & 31;
        const int rest = idx >> 5;
        const int pos = rest % 9, cc = rest / 9;
        wl[cc][pos][o] = wt[((o_base + o) * 3 + cc) * 9 + pos];
    }
    __syncthreads();

    float acc[4][8];
#pragma unroll
    for (int i = 0; i < 4; i++)
#pragma unroll
        for (int j = 0; j < 8; j++) acc[i][j] = 0.f;

#pragma unroll 2
    for (int cc = 0; cc < 3; cc++) {
        const float* src = x + ((size_t)b * 3 + cc) * HW;
#pragma unroll
        for (int dy = 0; dy < 3; dy++) {
            const int yy = y + dy - 1;
            float vv[10];
            if (yy >= 0 && yy < 256) {
                const float* r = src + (size_t)yy * WIDTH;
                vv[0] = (x0 > 0) ? r[x0 - 1] : 0.f;
                const float4 m0 = *(const float4*)(r + x0);
                const float4 m1 = *(const float4*)(r + x0 + 4);
                vv[1] = m0.x; vv[2] = m0.y; vv[3] = m0.z; vv[4] = m0.w;
                vv[5] = m1.x; vv[6] = m1.y; vv[7] = m1.z; vv[8] = m1.w;
                vv[9] = (x0 < 248) ? r[x0 + 8] : 0.f;
            } else {
#pragma unroll
                for (int q = 0; q < 10; q++) vv[q] = 0.f;
            }
#pragma unroll
            for (int dx = 0; dx < 3; dx++) {
                const float4 w4 = *(const float4*)&wl[cc][dy * 3 + dx][o0l];
                const float wv[4] = { w4.x, w4.y, w4.z, w4.w };
#pragma unroll
                for (int oi = 0; oi < 4; oi++)
#pragma unroll
                    for (int px = 0; px < 8; px++)
                        acc[oi][px] += wv[oi] * vv[px + dx];
            }
        }
    }
#pragma unroll
    for (int oi = 0; oi < 4; oi++) {
        const int o = o_base + o0l + oi;
        const float bv = bias[o];
        const size_t off = ((size_t)(b * 64 + o)) * HW + (size_t)y * WIDTH + x0;
        float4 r0, r1;
        r0.x = acc[oi][0] + bv; r0.y = acc[oi][1] + bv; r0.z = acc[oi][2] + bv; r0.w = acc[oi][3] + bv;
        r1.x = acc[oi][4] + bv; r1.y = acc[oi][5] + bv; r1.z = acc[oi][6] + bv; r1.w = acc[oi][7] + bv;
        *(float4*)(out + off) = r0;
        *(float4*)(out + off + 4) = r1;
        float s  = r0.x + r0.y + r0.z + r0.w + r1.x + r1.y + r1.z + r1.w;
        float s2 = r0.x*r0.x + r0.y*r0.y + r0.z*r0.z + r0.w*r0.w
                 + r1.x*r1.x + r1.y*r1.y + r1.z*r1.z + r1.w*r1.w;
#pragma unroll
        for (int offt = 16; offt > 0; offt >>= 1) {
            s  += __shfl_down(s, offt, 32);
            s2 += __shfl_down(s2, offt, 32);
        }
        if (xg == 0) {
            float* pp = &ps0[((b * 64 + o) * NSPLIT + split) * 2];
            atomicAdd(pp, s);
            atomicAdd(pp + 1, s2);
        }
    }
}

// ---------------- depthwise 3x3 + attention scale + fused stats(st1) ----------------
__global__ __launch_bounds__(256) void k_dw(const float* __restrict__ xp, const float* __restrict__ a2,
    const float* __restrict__ wref, const float* __restrict__ bref, float* __restrict__ out,
    float* __restrict__ ps1)
{
    const int tid = threadIdx.x;
    const int img = blockIdx.x >> 6;
    const int y = ((blockIdx.x & 63) << 2) + (tid >> 6);
    const int x0 = (tid & 63) * 4;
    const int c = img & 63;
    const int split = blockIdx.x & (NSPLIT - 1);
    const float* src = xp + (size_t)img * HW;
    float wv[9];
#pragma unroll
    for (int k = 0; k < 9; k++) wv[k] = wref[c * 9 + k];
    const float scale = a2[img], bb = bref[c];

    float a[4] = {0.f, 0.f, 0.f, 0.f};
#pragma unroll
    for (int dy = 0; dy < 3; dy++) {
        const int yy = y + dy - 1;
        if (yy < 0 || yy > 255) continue;
        const float* r = src + (size_t)yy * WIDTH;
        float vv[6];
        vv[0] = (x0 > 0) ? r[x0 - 1] : 0.f;
        const float4 m = *(const float4*)(r + x0);
        vv[1] = m.x; vv[2] = m.y; vv[3] = m.z; vv[4] = m.w;
        vv[5] = (x0 < 252) ? r[x0 + 4] : 0.f;
#pragma unroll
        for (int dx = 0; dx < 3; dx++)
#pragma unroll
            for (int px = 0; px < 4; px++)
                a[px] += wv[dy * 3 + dx] * vv[px + dx];
    }
    float4 o;
    o.x = bb + scale * a[0]; o.y = bb + scale * a[1];
    o.z = bb + scale * a[2]; o.w = bb + scale * a[3];
    *(float4*)(out + (size_t)img * HW + (size_t)y * WIDTH + x0) = o;

    float s  = o.x + o.y + o.z + o.w;
    float s2 = o.x*o.x + o.y*o.y + o.z*o.z + o.w*o.w;
#pragma unroll
    for (int offt = 32; offt > 0; offt >>= 1) {
        s  += __shfl_down(s, offt, 64);
        s2 += __shfl_down(s2, offt, 64);
    }
    __shared__ float ls[4][2];
    const int wid = tid >> 6, lane = tid & 63;
    if (lane == 0) { ls[wid][0] = s; ls[wid][1] = s2; }
    __syncthreads();
    if (tid == 0) {
        const float S  = ls[0][0] + ls[1][0] + ls[2][0] + ls[3][0];
        const float S2 = ls[0][1] + ls[1][1] + ls[2][1] + ls[3][1];
        float* pp = &ps1[(img * NSPLIT + split) * 2];
        atomicAdd(pp, S);
        atomicAdd(pp + 1, S2);
    }
}

// ---------------- Dirichlet kernel tables ----------------
__global__ void k_tables(float* __restrict__ kr2, float* __restrict__ ki2)
{
    const int t = blockIdx.x * 256 + threadIdx.x;
    if (t < 512) {
        const int tm = t & 255;
        const double PI = 3.14159265358979323846;
        const double th = 2.0 * PI * (double)tm / 256.0;
        double sr = 1.0;
        for (int k = 1; k <= 37; k++) sr += 2.0 * cos((double)k * th);
        sr += cos(38.0 * th);
        kr2[t] = (float)(sr / 256.0);
        ki2[t] = (float)(-sin(38.0 * th) / 256.0);
    }
}

// ---- circulant DFT matrices: KB[n][k] = f(n-k) ----
__global__ __launch_bounds__(256) void k_kmat(const float* __restrict__ kr2, const float* __restrict__ ki2,
    unsigned short* __restrict__ KBr, unsigned short* __restrict__ KBi)
{
    const int n = blockIdx.x, k = threadIdx.x;
    const int d = (n - k) & 255;
    KBr[n * 256 + k] = bf16u(kr2[d]);
    KBi[n * 256 + k] = bf16u(ki2[d]);
}

// ---------------- MFMA DFT pass 1 (x-direction), fp32 input with inline bf16 cvt ----------------
__global__ __launch_bounds__(256, 2) void k_mdft1(const float* __restrict__ xp,
    const unsigned short* __restrict__ KBr, const unsigned short* __restrict__ KBi,
    unsigned short* __restrict__ TR, unsigned short* __restrict__ TI)
{
    const int tid = threadIdx.x, lane = tid & 63, wave = tid >> 6;
    const int img = blockIdx.x >> 2;
    const int mb = (blockIdx.x >> 1) & 1, nb = blockIdx.x & 1;
    const int M0 = mb * 128 + (wave >> 1) * 64;
    const int N0 = nb * 128 + (wave & 1) * 64;
    const int lrow = lane & 15, lk = lane >> 4;
    const float* Xb = xp + (size_t)img * HW;

    f4v aR[4][4], aI[4][4];
#pragma unroll
    for (int m = 0; m < 4; m++)
#pragma unroll
        for (int n = 0; n < 4; n++) { aR[m][n] = (f4v){0,0,0,0}; aI[m][n] = (f4v){0,0,0,0}; }

#pragma unroll 1
    for (int k0 = 0; k0 < 256; k0 += 32) {
        bf8v af[4];
#pragma unroll
        for (int m = 0; m < 4; m++) {
            const float* rp = Xb + (size_t)(M0 + m * 16 + lrow) * 256 + k0 + lk * 8;
            const float4 a0 = *(const float4*)rp;
            const float4 a1 = *(const float4*)(rp + 4);
            bf8v t;
            t[0] = (short)bf16u(a0.x); t[1] = (short)bf16u(a0.y);
            t[2] = (short)bf16u(a0.z); t[3] = (short)bf16u(a0.w);
            t[4] = (short)bf16u(a1.x); t[5] = (short)bf16u(a1.y);
            t[6] = (short)bf16u(a1.z); t[7] = (short)bf16u(a1.w);
            af[m] = t;
        }
#pragma unroll
        for (int n = 0; n < 4; n++) {
            const int xcol = N0 + n * 16 + lrow;
            const bf8v br = *(const bf8v*)(KBr + xcol * 256 + k0 + lk * 8);
            const bf8v bi = *(const bf8v*)(KBi + xcol * 256 + k0 + lk * 8);
#pragma unroll
            for (int m = 0; m < 4; m++) {
                aR[m][n] = __builtin_amdgcn_mfma_f32_16x16x32_bf16(af[m], br, aR[m][n], 0, 0, 0);
                aI[m][n] = __builtin_amdgcn_mfma_f32_16x16x32_bf16(af[m], bi, aI[m][n], 0, 0, 0);
            }
        }
    }
#pragma unroll
    for (int n = 0; n < 4; n++) {
        const size_t xoff = (size_t)img * HW + (size_t)(N0 + n * 16 + lrow) * 256;
#pragma unroll
        for (int m = 0; m < 4; m++) {
            const size_t off = xoff + M0 + m * 16 + lk * 4;
            const f4v r = aR[m][n], ii = aI[m][n];
            ushort4 ur, ui;
            ur.x = bf16u(r[0]); ur.y = bf16u(r[1]); ur.z = bf16u(r[2]); ur.w = bf16u(r[3]);
            ui.x = bf16u(ii[0]); ui.y = bf16u(ii[1]); ui.z = bf16u(ii[2]); ui.w = bf16u(ii[3]);
            *(ushort4*)(TR + off) = ur;
            *(ushort4*)(TI + off) = ui;
        }
    }
}

// ---------------- MFMA DFT pass 2 (y-direction) ----------------
__global__ __launch_bounds__(256, 2) void k_mdft2(const unsigned short* __restrict__ TR,
    const unsigned short* __restrict__ TI, const unsigned short* __restrict__ KBr,
    const unsigned short* __restrict__ KBi, float* __restrict__ low)
{
    const int tid = threadIdx.x, lane = tid & 63, wave = tid >> 6;
    const int img = blockIdx.x >> 2;
    const int mb = (blockIdx.x >> 1) & 1, nb = blockIdx.x & 1;
    const int M0 = mb * 128 + (wave >> 1) * 64;
    const int N0 = nb * 128 + (wave & 1) * 64;
    const int lrow = lane & 15, lk = lane >> 4;
    const unsigned short* TRb = TR + (size_t)img * HW;
    const unsigned short* TIb = TI + (size_t)img * HW;

    f4v aR[4][4], aI[4][4];
#pragma unroll
    for (int m = 0; m < 4; m++)
#pragma unroll
        for (int n = 0; n < 4; n++) { aR[m][n] = (f4v){0,0,0,0}; aI[m][n] = (f4v){0,0,0,0}; }

#pragma unroll 1
    for (int k0 = 0; k0 < 256; k0 += 32) {
        bf8v afR[4], afI[4];
#pragma unroll
        for (int m = 0; m < 4; m++) {
            const int ro = (M0 + m * 16 + lrow) * 256 + k0 + lk * 8;
            afR[m] = *(const bf8v*)(TRb + ro);
            afI[m] = *(const bf8v*)(TIb + ro);
        }
#pragma unroll
        for (int n = 0; n < 4; n++) {
            const int ycol = N0 + n * 16 + lrow;
            const bf8v br = *(const bf8v*)(KBr + ycol * 256 + k0 + lk * 8);
            const bf8v bi = *(const bf8v*)(KBi + ycol * 256 + k0 + lk * 8);
#pragma unroll
            for (int m = 0; m < 4; m++) {
                aR[m][n] = __builtin_amdgcn_mfma_f32_16x16x32_bf16(afR[m], br, aR[m][n], 0, 0, 0);
                aI[m][n] = __builtin_amdgcn_mfma_f32_16x16x32_bf16(afI[m], bi, aI[m][n], 0, 0, 0);
            }
        }
    }
#pragma unroll
    for (int n = 0; n < 4; n++) {
        const size_t yoff = (size_t)img * HW + (size_t)(N0 + n * 16 + lrow) * 256;
#pragma unroll
        for (int m = 0; m < 4; m++) {
            const f4v r = aR[m][n], ii = aI[m][n];
            const float4 v = make_float4(r[0] - ii[0], r[1] - ii[1], r[2] - ii[2], r[3] - ii[3]);
            *(float4*)(low + yoff + M0 + m * 16 + lk * 4) = v;
        }
    }
}

// ---- W_eff = collapse(grouped 3x3, 1x1) -> bf16 [chunk][pos][oc][ch] ----
__global__ __launch_bounds__(256) void k_weff_bf(const float* __restrict__ w_u1,
    const float* __restrict__ w_con, unsigned short* __restrict__ wbf)
{
    const int f = blockIdx.x * 256 + threadIdx.x;
    if (f >= 73728) return;
    const int ch = f & 31, oc = (f >> 5) & 63, cp = f >> 11;
    const int pos = cp % 9, cb = cp / 9;
    const int g = cb * 32 + ch;
    float s = 0.f;
#pragma unroll
    for (int j = 0; j < 4; j++) s += w_u1[oc * 512 + g * 4 + j] * w_con[(g * 4 + j) * 9 + pos];
    wbf[f] = bf16u(s);
}

// ---- fp32 OIHW 3x3 weights -> bf16 [chunk][pos][oc][ch] ----
template<int CIN>
__global__ __launch_bounds__(256) void k_wcvt(const float* __restrict__ w, unsigned short* __restrict__ wbf)
{
    const int f = blockIdx.x * 256 + threadIdx.x;
    if (f >= 64 * CIN * 9) return;
    const int ch = f & 31, oc = (f >> 5) & 63, cp = f >> 11;
    const int pos = cp % 9, cb = cp / 9;
    const int c = cb * 32 + ch;
    wbf[f] = bf16u(w[oc * CIN * 9 + c * 9 + pos]);
}

// ---- fp32 1x1 weights [oc][CIN] -> bf16 [cb][oc][32ch] ----
template<int CIN>
__global__ __launch_bounds__(256) void k_wcvt1(const float* __restrict__ w, unsigned short* __restrict__ wbf)
{
    const int f = blockIdx.x * 256 + threadIdx.x;   // 64*CIN
    if (f >= 64 * CIN) return;
    const int ch = f & 31, oc = (f >> 5) & 63, cb = f >> 11;
    wbf[f] = bf16u(w[oc * CIN + cb * 32 + ch]);
}

// ---------------- MFMA 3x3 conv with fused norm-on-load + stats-on-store ----------------
// R13 kept 256-px x 2-row block (FETCH ~131 MB), 512 thr / 8 waves (4/SIMD).
// R14: staging remapped (4px x 8ch)/thread: 64 scalar loads -> 16 float4; the 4 packed
// dwords of one ch-group land contiguous in a 16B slot -> one uint4 LDS write per
// (row,px). Layout (incl. XOR swizzle) bit-identical to R13.
template<int CIN>
__global__ __launch_bounds__(512, 4) void k_mconv(
    const float* __restrict__ in0, const float* __restrict__ in1,
    const unsigned short* __restrict__ wbf, const float* __restrict__ bias,
    float* __restrict__ out,
    const float* __restrict__ stA, const float* __restrict__ stB,
    float* __restrict__ psOut)
{
    __shared__ unsigned short Xl[4 * 260 * 32];   // row stride 16640 B
    __shared__ float sh_ms[2 * CIN];
    __shared__ float red[8][64][2];
    const int tid = threadIdx.x;
    const int lane = tid & 63;
    const int wave = tid >> 6;                 // 0..7
    const int b = blockIdx.x >> 7;
    const int y0 = (blockIdx.x & 127) * 2;
    const int row_sel = wave & 1;              // output row within pair
    const int px_base = (wave >> 1) * 64;      // px quarter
    const int split = blockIdx.x & (NSPLIT - 1);

    for (int i = tid; i < 4 * 260 * 32 / 2; i += 512) ((unsigned int*)Xl)[i] = 0u;
    for (int j = tid; j < 2 * CIN; j += 512) {
        const int cg = j >> 1;
        const float* st = (CIN == 128 && cg >= 64) ? stB : stA;
        sh_ms[j] = st[(b * 64 + (cg & 63)) * 2 + (j & 1)];
    }

    f4v acc[4][4];
#pragma unroll
    for (int i = 0; i < 4; i++)
#pragma unroll
        for (int n = 0; n < 4; n++) acc[i][n] = (f4v){0.f, 0.f, 0.f, 0.f};

    const int lrow = lane & 15;
    const int gsl  = lane >> 4;
    const int wlane = lrow * 32 + gsl * 8;

    __syncthreads();    // init + sh_ms visible

    constexpr int NC = CIN / 32;
#pragma unroll 1
    for (int cb = 0; cb < NC; cb++) {
        const int c0 = cb * 32;
        const bool second = (CIN == 128 && c0 >= 64);
        const float* src = (second ? in1 : in0) + ((size_t)b * 64 + (c0 & 63)) * HW;
        const float* ms = sh_ms + cb * 64;
        {   // stage 4 rows x 256 px x 32 ch: thread = (px quad, 8-ch group, row pair)
            const int q   = tid & 63;
            const int g   = (tid >> 6) & 3;
            const int rg  = tid >> 8;
            const int px0 = q * 4;
#pragma unroll
            for (int r2 = 0; r2 < 2; r2++) {
                const int r = rg * 2 + r2;
                const int yy = y0 - 1 + r;
                if (yy < 0 || yy > 255) continue;
                const float* rp = src + (size_t)(g * 8) * HW + (size_t)yy * WIDTH + px0;
                float v[8][4];
#pragma unroll
                for (int cc = 0; cc < 8; cc++) {
                    const float4 ld = *(const float4*)(rp + (size_t)cc * HW);
                    const float mm  = ms[(g * 8 + cc) * 2];
                    const float ssv = ms[(g * 8 + cc) * 2 + 1];
                    v[cc][0] = lrelu_f((ld.x - mm) * ssv);
                    v[cc][1] = lrelu_f((ld.y - mm) * ssv);
                    v[cc][2] = lrelu_f((ld.z - mm) * ssv);
                    v[cc][3] = lrelu_f((ld.w - mm) * ssv);
                }
#pragma unroll
                for (int p = 0; p < 4; p++) {
                    const int slot = px0 + p + 1;
                    const int sw = (slot >> 1) & 3;
                    uint4 w4;
                    w4.x = (unsigned)bf16u(v[0][p]) | ((unsigned)bf16u(v[1][p]) << 16);
                    w4.y = (unsigned)bf16u(v[2][p]) | ((unsigned)bf16u(v[3][p]) << 16);
                    w4.z = (unsigned)bf16u(v[4][p]) | ((unsigned)bf16u(v[5][p]) << 16);
                    w4.w = (unsigned)bf16u(v[6][p]) | ((unsigned)bf16u(v[7][p]) << 16);
                    *(uint4*)((char*)Xl + r * 16640 + slot * 64 + ((g ^ sw) << 4)) = w4;
                }
            }
        }
        __syncthreads();
#pragma unroll 1
        for (int pos = 0; pos < 9; pos++) {
            const int dy = pos / 3, dx = pos - dy * 3;
            const unsigned short* wp = wbf + (cb * 9 + pos) * 2048 + wlane;
            const bf8v wf0 = *(const bf8v*)(wp);
            const bf8v wf1 = *(const bf8v*)(wp + 512);
            const bf8v wf2 = *(const bf8v*)(wp + 1024);
            const bf8v wf3 = *(const bf8v*)(wp + 1536);
            const int pxe = px_base + lrow + dx;           // slot = px+1 with dx-1 offset
            const int row = row_sel + dy;
            const char* abase = (const char*)Xl + row * 16640 + pxe * 64
                              + ((gsl ^ ((pxe >> 1) & 3)) << 4);
#pragma unroll
            for (int i = 0; i < 4; i++) {
                const bf8v af = *(const bf8v*)(abase + i * 1024);   // +16 px: swizzle invariant
                acc[i][0] = __builtin_amdgcn_mfma_f32_16x16x32_bf16(af, wf0, acc[i][0], 0, 0, 0);
                acc[i][1] = __builtin_amdgcn_mfma_f32_16x16x32_bf16(af, wf1, acc[i][1], 0, 0, 0);
                acc[i][2] = __builtin_amdgcn_mfma_f32_16x16x32_bf16(af, wf2, acc[i][2], 0, 0, 0);
                acc[i][3] = __builtin_amdgcn_mfma_f32_16x16x32_bf16(af, wf3, acc[i][3], 0, 0, 0);
            }
        }
        __syncthreads();
    }
    // epilogue: store + per-oc stats
    const int yrow = y0 + row_sel;
    const int lk = gsl;
#pragma unroll
    for (int n = 0; n < 4; n++) {
        const float bv = bias[n * 16 + lrow];
        float* po = out + ((size_t)(b * 64) + n * 16 + lrow) * HW
                  + (size_t)yrow * WIDTH + px_base + lk * 4;
        float s = 0.f, s2 = 0.f;
#pragma unroll
        for (int i = 0; i < 4; i++) {
            const f4v a = acc[i][n];
            float4 v;
            v.x = a[0] + bv; v.y = a[1] + bv; v.z = a[2] + bv; v.w = a[3] + bv;
            s  += v.x + v.y + v.z + v.w;
            s2 += v.x*v.x + v.y*v.y + v.z*v.z + v.w*v.w;
            *(float4*)(po + i * 16) = v;
        }
        s  += __shfl_down(s, 32);  s  += __shfl_down(s, 16);
        s2 += __shfl_down(s2, 32); s2 += __shfl_down(s2, 16);
        if (lk == 0) { red[wave][n * 16 + lrow][0] = s; red[wave][n * 16 + lrow][1] = s2; }
    }
    __syncthreads();
    if (tid < 64) {
        float S = 0.f, S2 = 0.f;
#pragma unroll
        for (int w = 0; w < 8; w++) { S += red[w][tid][0]; S2 += red[w][tid][1]; }
        float* pp = &psOut[((b * 64 + tid) * NSPLIT + split) * 2];
        atomicAdd(pp, S);
        atomicAdd(pp + 1, S2);
    }
}

// ---------------- MFMA pointwise (1x1) conv ----------------
// R14: staging remapped (4px x 8ch)/thread as in k_mconv: 8 float4 loads + 4 uint4
// LDS writes per chunk (was 32 scalar + 16 dword). Layout unchanged.
template<int CIN, bool ADD, bool NORMIN, bool STATS>
__global__ __launch_bounds__(256, 3) void k_pconv(
    const float* __restrict__ in0, const float* __restrict__ in1,
    const unsigned short* __restrict__ wbf, const float* __restrict__ bias,
    const float* __restrict__ addsrc, float* __restrict__ out,
    const float* __restrict__ stA, const float* __restrict__ stB,
    const float* __restrict__ stAdd, float* __restrict__ psOut)
{
    __shared__ unsigned short Xl[256 * 32];      // [px][32ch], 16B-slot swizzled
    __shared__ float sh_ms[2 * CIN];
    __shared__ float red[4][64][2];
    const int tid = threadIdx.x, lane = tid & 63, wave = tid >> 6;
    const int y = blockIdx.x & 255, b = blockIdx.x >> 8;
    const int split = blockIdx.x & (NSPLIT - 1);
    const int lrow = lane & 15, gsl = lane >> 4;
    const int wpx = wave * 64;
    const int wlane = lrow * 32 + gsl * 8;

    if constexpr (NORMIN) {
        for (int j = tid; j < 2 * CIN; j += 256) {
            const int cg = j >> 1;
            const float* st = (CIN == 128 && cg >= 64) ? stB : stA;
            sh_ms[j] = st[(b * 64 + (cg & 63)) * 2 + (j & 1)];
        }
    }

    f4v acc[4][4];
#pragma unroll
    for (int m = 0; m < 4; m++)
#pragma unroll
        for (int n = 0; n < 4; n++) acc[m][n] = (f4v){0.f, 0.f, 0.f, 0.f};

    __syncthreads();

    constexpr int NC = CIN / 32;
#pragma unroll 1
    for (int cb = 0; cb < NC; cb++) {
        const int c0 = cb * 32;
        const bool second = (CIN == 128 && c0 >= 64);
        const float* src = (second ? in1 : in0) + ((size_t)b * 64 + (c0 & 63)) * HW
                         + (size_t)y * WIDTH;
        const float* ms = sh_ms + cb * 64;
        {   // stage 256 px x 32 ch: thread = (px quad, 8-ch group)
            const int q = tid & 63, g = tid >> 6;
            const int px0 = q * 4;
            const float* rp = src + (size_t)(g * 8) * HW + px0;
            float v[8][4];
#pragma unroll
            for (int cc = 0; cc < 8; cc++) {
                const float4 ld = *(const float4*)(rp + (size_t)cc * HW);
                if constexpr (NORMIN) {
                    const float mm  = ms[(g * 8 + cc) * 2];
                    const float ssv = ms[(g * 8 + cc) * 2 + 1];
                    v[cc][0] = lrelu_f((ld.x - mm) * ssv);
                    v[cc][1] = lrelu_f((ld.y - mm) * ssv);
                    v[cc][2] = lrelu_f((ld.z - mm) * ssv);
                    v[cc][3] = lrelu_f((ld.w - mm) * ssv);
                } else {
                    v[cc][0] = ld.x; v[cc][1] = ld.y; v[cc][2] = ld.z; v[cc][3] = ld.w;
                }
            }
#pragma unroll
            for (int p = 0; p < 4; p++) {
                const int px = px0 + p;
                const int sw = (px >> 1) & 3;
                uint4 w4;
                w4.x = (unsigned)bf16u(v[0][p]) | ((unsigned)bf16u(v[1][p]) << 16);
                w4.y = (unsigned)bf16u(v[2][p]) | ((unsigned)bf16u(v[3][p]) << 16);
                w4.z = (unsigned)bf16u(v[4][p]) | ((unsigned)bf16u(v[5][p]) << 16);
                w4.w = (unsigned)bf16u(v[6][p]) | ((unsigned)bf16u(v[7][p]) << 16);
                *(uint4*)((char*)Xl + px * 64 + ((g ^ sw) << 4)) = w4;
            }
        }
        __syncthreads();
        {
            const unsigned short* wp = wbf + cb * 2048 + wlane;
            const bf8v wf0 = *(const bf8v*)(wp);
            const bf8v wf1 = *(const bf8v*)(wp + 512);
            const bf8v wf2 = *(const bf8v*)(wp + 1024);
            const bf8v wf3 = *(const bf8v*)(wp + 1536);
#pragma unroll
            for (int m = 0; m < 4; m++) {
                const int px = wpx + m * 16 + lrow;
                const char* abase = (const char*)Xl + px * 64
                                  + ((gsl ^ ((px >> 1) & 3)) << 4);
                const bf8v af = *(const bf8v*)abase;
                acc[m][0] = __builtin_amdgcn_mfma_f32_16x16x32_bf16(af, wf0, acc[m][0], 0, 0, 0);
                acc[m][1] = __builtin_amdgcn_mfma_f32_16x16x32_bf16(af, wf1, acc[m][1], 0, 0, 0);
                acc[m][2] = __builtin_amdgcn_mfma_f32_16x16x32_bf16(af, wf2, acc[m][2], 0, 0, 0);
                acc[m][3] = __builtin_amdgcn_mfma_f32_16x16x32_bf16(af, wf3, acc[m][3], 0, 0, 0);
            }
        }
        __syncthreads();
    }
    // epilogue: bias (+ normed residual) + store (+ stats)
    const int lk = gsl;
#pragma unroll
    for (int n = 0; n < 4; n++) {
        const int oc = n * 16 + lrow;
        const float bv = bias[oc];
        float mm = 0.f, ss = 0.f;
        if constexpr (ADD) { mm = stAdd[(b * 64 + oc) * 2]; ss = stAdd[(b * 64 + oc) * 2 + 1]; }
        const size_t orow = ((size_t)(b * 64 + oc)) * HW + (size_t)y * WIDTH;
        float s = 0.f, s2 = 0.f;
#pragma unroll
        for (int m = 0; m < 4; m++) {
            const int px = wpx + m * 16 + lk * 4;
            const f4v a = acc[m][n];
            float r[4] = { a[0] + bv, a[1] + bv, a[2] + bv, a[3] + bv };
            if constexpr (ADD) {
                const float4 av = *(const float4*)(addsrc + orow + px);
                r[0] += lrelu_f((av.x - mm) * ss);
                r[1] += lrelu_f((av.y - mm) * ss);
                r[2] += lrelu_f((av.z - mm) * ss);
                r[3] += lrelu_f((av.w - mm) * ss);
            }
            *(float4*)(out + orow + px) = make_float4(r[0], r[1], r[2], r[3]);
            if constexpr (STATS) {
                s  += r[0] + r[1] + r[2] + r[3];
                s2 += r[0]*r[0] + r[1]*r[1] + r[2]*r[2] + r[3]*r[3];
            }
        }
        if constexpr (STATS) {
            s  += __shfl_down(s, 32);  s  += __shfl_down(s, 16);
            s2 += __shfl_down(s2, 32); s2 += __shfl_down(s2, 16);
            if (lk == 0) { red[wave][oc][0] = s; red[wave][oc][1] = s2; }
        }
    }
    if constexpr (STATS) {
        __syncthreads();
        if (tid < 64) {
            const float S  = red[0][tid][0] + red[1][tid][0] + red[2][tid][0] + red[3][tid][0];
            const float S2 = red[0][tid][1] + red[1][tid][1] + red[2][tid][1] + red[3][tid][1];
            float* pp = &psOut[((b * 64 + tid) * NSPLIT + split) * 2];
            atomicAdd(pp, S);
            atomicAdd(pp + 1, S2);
        }
    }
}

// ---------------- 2x2 max pool ----------------
__global__ __launch_bounds__(256) void k_maxpool(const float* __restrict__ feat, float* __restrict__ out)
{
    const int idx = blockIdx.x * 256 + threadIdx.x;
    const int xo = idx & 127;
    const int yo = (idx >> 7) & 127;
    const int img = idx >> 14;
    const float* p = feat + (size_t)img * HW + (size_t)(yo * 2) * WIDTH + xo * 2;
    out[idx] = fmaxf(fmaxf(p[0], p[1]), fmaxf(p[WIDTH], p[WIDTH + 1]));
}

extern "C" void kernel_launch(void* const* d_in, const int* in_sizes, int n_in,
                              void* d_out, int out_size, void* d_ws, size_t ws_size,
                              hipStream_t stream)
{
    const float* x      = (const float*)d_in[0];
    const float* w_proj = (const float*)d_in[1];
    const float* b_proj = (const float*)d_in[2];
    const float* w_a1   = (const float*)d_in[3];
    const float* w_a2   = (const float*)d_in[4];
    const float* w_ref  = (const float*)d_in[5];
    const float* b_ref  = (const float*)d_in[6];
    const float* w_fuse = (const float*)d_in[7];
    const float* b_fuse = (const float*)d_in[8];
    const float* w_con  = (const float*)d_in[9];
    const float* w_u1   = (const float*)d_in[10];
    const float* b_u1   = (const float*)d_in[11];
    const float* w_u2   = (const float*)d_in[12];
    const float* b_u2   = (const float*)d_in[13];
    const float* w_sc   = (const float*)d_in[14];
    const float* b_sc   = (const float*)d_in[15];

    float* wsf  = (float*)d_ws;
    float* buf0 = wsf;                       // xp -> fuse_raw
    float* buf1 = wsf + (size_t)IMG;         // xw raw
    float* buf2 = wsf + (size_t)2 * IMG;     // T1R/T1I bf16 overlay -> u2raw
    float* aux  = wsf + (size_t)3 * IMG;
    float* a2b  = aux;                       // 256
    float* kr2  = aux + 256;                 // 512
    float* ki2  = aux + 768;                 // 512
    unsigned short* wbfA = (unsigned short*)(aux + 1280);    // 73728 ushort
    unsigned short* wbfB = wbfA + 73728;                     // 36864 ushort
    unsigned short* KBr  = wbfB + 36864;                     // 65536 ushort
    unsigned short* KBi  = KBr + 65536;                      // 65536 ushort
    unsigned short* wbfF = KBi + 65536;                      // 4096 ushort (fuse 1x1)
    unsigned short* wbfS = wbfF + 4096;                      // 8192 ushort (sc 1x1)
    float* ps   = aux + 1280 + 120832 + 6144;  // 5 slots x 256 imgs x NSPLIT x 2
    float* st   = ps + 5 * 256 * NSPLIT * 2;   // 5 slots x 256 x 2

    float* fout = (float*)d_out;             // low -> u1raw -> feat
    float* pout = fout + (size_t)IMG;        // pooled
    unsigned short* T1R = (unsigned short*)buf2;
    unsigned short* T1I = T1R + (size_t)IMG;

    const int PSSLOT = 256 * NSPLIT * 2;     // 8192 floats per slot

    hipMemsetAsync(ps, 0, 5 * PSSLOT * sizeof(float), stream);
    k_tables<<<2, 256, 0, stream>>>(kr2, ki2);
    k_kmat<<<256, 256, 0, stream>>>(kr2, ki2, KBr, KBi);
    k_weff_bf<<<288, 256, 0, stream>>>(w_u1, w_con, wbfA);
    k_wcvt<64><<<144, 256, 0, stream>>>(w_u2, wbfB);
    k_wcvt1<64><<<16, 256, 0, stream>>>(w_fuse, wbfF);
    k_wcvt1<128><<<32, 256, 0, stream>>>(w_sc, wbfS);
    k_proj<<<2048, 256, 0, stream>>>(x, w_proj, b_proj, buf0, ps);
    k_attention<<<1, 256, 0, stream>>>(ps, w_a1, w_a2, a2b);
    k_dw<<<16384, 256, 0, stream>>>(buf0, a2b, w_ref, b_ref, buf1, ps + PSSLOT);
    k_mdft1<<<1024, 256, 0, stream>>>(buf0, KBr, KBi, T1R, T1I);
    k_mdft2<<<1024, 256, 0, stream>>>(T1R, T1I, KBr, KBi, fout);
    k_pconv<64, false, false, true><<<1024, 256, 0, stream>>>(
        fout, nullptr, wbfF, b_fuse, nullptr, buf0,
        nullptr, nullptr, nullptr, ps + 2 * PSSLOT);
    k_statsf<<<2, 256, 0, stream>>>(ps + PSSLOT, st + 512);       // st1 (dw), st2 (fuse)
    k_mconv<128><<<512, 512, 0, stream>>>(buf1, buf0, wbfA, b_u1, fout,
        st + 512, st + 1024, ps + 3 * PSSLOT);
    k_statsf<<<1, 256, 0, stream>>>(ps + 3 * PSSLOT, st + 1536);  // st3
    k_mconv<64><<<512, 512, 0, stream>>>(fout, nullptr, wbfB, b_u2, buf2,
        st + 1536, st + 1536, ps + 4 * PSSLOT);
    k_statsf<<<1, 256, 0, stream>>>(ps + 4 * PSSLOT, st + 2048);  // st4
    k_pconv<128, true, true, false><<<1024, 256, 0, stream>>>(
        buf1, buf0, wbfS, b_sc, buf2, fout,
        st + 512, st + 1024, st + 2048, nullptr);
    k_maxpool<<<16384, 256, 0, stream>>>(fout, pout);
}

// Round 15
// 491.117 us; speedup vs baseline: 1.0827x; 1.0827x over previous
//
#include <hip/hip_runtime.h>
#include <hip/hip_bf16.h>

#define WIDTH 256
#define HW 65536
#define IMG 16777216   // 4*64*HW
#define NIMG 256
#define NSPLIT 16      // stats shards per image: cuts same-address atomic chains 16x (R9: 256-deep chains => 189us)

typedef __attribute__((ext_vector_type(8))) short bf8v;   // 8 bf16 = 4 VGPR (MFMA A/B frag)
typedef __attribute__((ext_vector_type(4))) float f4v;    // 4 f32 (MFMA C/D frag)

__device__ __forceinline__ float lrelu_f(float v){ return v > 0.f ? v : 0.01f*v; }
__device__ __forceinline__ unsigned short bf16u(float v){
    __hip_bfloat16 h = __float2bfloat16(v);
    return *(unsigned short*)&h;
}

// ---------------- stats finalize: ps (256 imgs x 16 splits x 2 sums) -> st (mean, inv_std) ----------------
__global__ __launch_bounds__(256) void k_statsf(const float* __restrict__ ps, float* __restrict__ st)
{
    const int img = threadIdx.x;
    const float* p = ps + blockIdx.x * (256 * NSPLIT * 2) + img * (NSPLIT * 2);
    float* o = st + blockIdx.x * 512;
    float S = 0.f, S2 = 0.f;
#pragma unroll
    for (int q = 0; q < NSPLIT; q++) { S += p[q * 2]; S2 += p[q * 2 + 1]; }
    const float m = S / 65536.f;
    const float var = S2 / 65536.f - m * m;
    o[img * 2]     = m;
    o[img * 2 + 1] = rsqrtf(var + 1e-5f);
}

// ---------------- attention MLP (single block; reads sharded raw sums, needs means only) ----------------
__global__ __launch_bounds__(256) void k_attention(const float* __restrict__ ps0,
    const float* __restrict__ wa1, const float* __restrict__ wa2, float* __restrict__ a2o)
{
    __shared__ float means[256];
    __shared__ float a1s[64];
    const int tid = threadIdx.x;
    {
        const float* p = ps0 + tid * (NSPLIT * 2);
        float S = 0.f;
#pragma unroll
        for (int q = 0; q < NSPLIT; q++) S += p[q * 2];
        means[tid] = S * (1.f / 65536.f);
    }
    __syncthreads();
    if (tid < 64) {
        const int b = tid >> 4, o = tid & 15;
        float s = 0.f;
        for (int c = 0; c < 64; c++) s += wa1[o * 64 + c] * means[b * 64 + c];
        a1s[b * 16 + o] = lrelu_f(s);
    }
    __syncthreads();
    {
        const int b = tid >> 6, c = tid & 63;
        float s = 0.f;
#pragma unroll
        for (int o = 0; o < 16; o++) s += wa2[c * 16 + o] * a1s[b * 16 + o];
        a2o[tid] = 1.f / (1.f + expf(-s));
    }
}

// ---------------- proj conv 3->64 3x3 + fused stats(st0) ----------------
// NOTE: cc loop must stay `#pragma unroll 2` — R7/R8 full-unrolled it; with the
// (256,3) VGPR cap (84) the ~90 hoisted loads spilled to scratch (552 MB WRITE).
__global__ __launch_bounds__(256, 3) void k_proj(const float* __restrict__ x,
    const float* __restrict__ wt, const float* __restrict__ bias,
    float* __restrict__ out, float* __restrict__ ps0)
{
    __shared__ float wl[3][9][32];
    const int tid = threadIdx.x;
    const int og = tid >> 5, xg = tid & 31;
    const int half = blockIdx.x & 1;
    const int y = (blockIdx.x >> 1) & 255;
    const int b = blockIdx.x >> 9;
    const int o_base = half * 32;
    const int o0l = og * 4;
    const int x0 = xg * 8;
    const int split = y & (NSPLIT - 1);

    for (int idx = tid; idx < 3 * 9 * 32; idx += 256) {
        const int o = idx & 31;
        const int rest = idx >> 5;
        const int pos = rest % 9, cc = rest / 9;
        wl[cc][pos][o] = wt[((o_base + o) * 3 + cc) * 9 + pos];
    }
    __syncthreads();

    float acc[4][8];
#pragma unroll
    for (int i = 0; i < 4; i++)
#pragma unroll
        for (int j = 0; j < 8; j++) acc[i][j] = 0.f;

#pragma unroll 2
    for (int cc = 0; cc < 3; cc++) {
        const float* src = x + ((size_t)b * 3 + cc) * HW;
#pragma unroll
        for (int dy = 0; dy < 3; dy++) {
            const int yy = y + dy - 1;
            float vv[10];
            if (yy >= 0 && yy < 256) {
                const float* r = src + (size_t)yy * WIDTH;
                vv[0] = (x0 > 0) ? r[x0 - 1] : 0.f;
                const float4 m0 = *(const float4*)(r + x0);
                const float4 m1 = *(const float4*)(r + x0 + 4);
                vv[1] = m0.x; vv[2] = m0.y; vv[3] = m0.z; vv[4] = m0.w;
                vv[5] = m1.x; vv[6] = m1.y; vv[7] = m1.z; vv[8] = m1.w;
                vv[9] = (x0 < 248) ? r[x0 + 8] : 0.f;
            } else {
#pragma unroll
                for (int q = 0; q < 10; q++) vv[q] = 0.f;
            }
#pragma unroll
            for (int dx = 0; dx < 3; dx++) {
                const float4 w4 = *(const float4*)&wl[cc][dy * 3 + dx][o0l];
                const float wv[4] = { w4.x, w4.y, w4.z, w4.w };
#pragma unroll
                for (int oi = 0; oi < 4; oi++)
#pragma unroll
                    for (int px = 0; px < 8; px++)
                        acc[oi][px] += wv[oi] * vv[px + dx];
            }
        }
    }
#pragma unroll
    for (int oi = 0; oi < 4; oi++) {
        const int o = o_base + o0l + oi;
        const float bv = bias[o];
        const size_t off = ((size_t)(b * 64 + o)) * HW + (size_t)y * WIDTH + x0;
        float4 r0, r1;
        r0.x = acc[oi][0] + bv; r0.y = acc[oi][1] + bv; r0.z = acc[oi][2] + bv; r0.w = acc[oi][3] + bv;
        r1.x = acc[oi][4] + bv; r1.y = acc[oi][5] + bv; r1.z = acc[oi][6] + bv; r1.w = acc[oi][7] + bv;
        *(float4*)(out + off) = r0;
        *(float4*)(out + off + 4) = r1;
        float s  = r0.x + r0.y + r0.z + r0.w + r1.x + r1.y + r1.z + r1.w;
        float s2 = r0.x*r0.x + r0.y*r0.y + r0.z*r0.z + r0.w*r0.w
                 + r1.x*r1.x + r1.y*r1.y + r1.z*r1.z + r1.w*r1.w;
#pragma unroll
        for (int offt = 16; offt > 0; offt >>= 1) {
            s  += __shfl_down(s, offt, 32);
            s2 += __shfl_down(s2, offt, 32);
        }
        if (xg == 0) {
            float* pp = &ps0[((b * 64 + o) * NSPLIT + split) * 2];
            atomicAdd(pp, s);
            atomicAdd(pp + 1, s2);
        }
    }
}

// ---------------- depthwise 3x3 + attention scale + fused stats(st1) ----------------
__global__ __launch_bounds__(256) void k_dw(const float* __restrict__ xp, const float* __restrict__ a2,
    const float* __restrict__ wref, const float* __restrict__ bref, float* __restrict__ out,
    float* __restrict__ ps1)
{
    const int tid = threadIdx.x;
    const int img = blockIdx.x >> 6;
    const int y = ((blockIdx.x & 63) << 2) + (tid >> 6);
    const int x0 = (tid & 63) * 4;
    const int c = img & 63;
    const int split = blockIdx.x & (NSPLIT - 1);
    const float* src = xp + (size_t)img * HW;
    float wv[9];
#pragma unroll
    for (int k = 0; k < 9; k++) wv[k] = wref[c * 9 + k];
    const float scale = a2[img], bb = bref[c];

    float a[4] = {0.f, 0.f, 0.f, 0.f};
#pragma unroll
    for (int dy = 0; dy < 3; dy++) {
        const int yy = y + dy - 1;
        if (yy < 0 || yy > 255) continue;
        const float* r = src + (size_t)yy * WIDTH;
        float vv[6];
        vv[0] = (x0 > 0) ? r[x0 - 1] : 0.f;
        const float4 m = *(const float4*)(r + x0);
        vv[1] = m.x; vv[2] = m.y; vv[3] = m.z; vv[4] = m.w;
        vv[5] = (x0 < 252) ? r[x0 + 4] : 0.f;
#pragma unroll
        for (int dx = 0; dx < 3; dx++)
#pragma unroll
            for (int px = 0; px < 4; px++)
                a[px] += wv[dy * 3 + dx] * vv[px + dx];
    }
    float4 o;
    o.x = bb + scale * a[0]; o.y = bb + scale * a[1];
    o.z = bb + scale * a[2]; o.w = bb + scale * a[3];
    *(float4*)(out + (size_t)img * HW + (size_t)y * WIDTH + x0) = o;

    float s  = o.x + o.y + o.z + o.w;
    float s2 = o.x*o.x + o.y*o.y + o.z*o.z + o.w*o.w;
#pragma unroll
    for (int offt = 32; offt > 0; offt >>= 1) {
        s  += __shfl_down(s, offt, 64);
        s2 += __shfl_down(s2, offt, 64);
    }
    __shared__ float ls[4][2];
    const int wid = tid >> 6, lane = tid & 63;
    if (lane == 0) { ls[wid][0] = s; ls[wid][1] = s2; }
    __syncthreads();
    if (tid == 0) {
        const float S  = ls[0][0] + ls[1][0] + ls[2][0] + ls[3][0];
        const float S2 = ls[0][1] + ls[1][1] + ls[2][1] + ls[3][1];
        float* pp = &ps1[(img * NSPLIT + split) * 2];
        atomicAdd(pp, S);
        atomicAdd(pp + 1, S2);
    }
}

// ---------------- Dirichlet kernel tables ----------------
__global__ void k_tables(float* __restrict__ kr2, float* __restrict__ ki2)
{
    const int t = blockIdx.x * 256 + threadIdx.x;
    if (t < 512) {
        const int tm = t & 255;
        const double PI = 3.14159265358979323846;
        const double th = 2.0 * PI * (double)tm / 256.0;
        double sr = 1.0;
        for (int k = 1; k <= 37; k++) sr += 2.0 * cos((double)k * th);
        sr += cos(38.0 * th);
        kr2[t] = (float)(sr / 256.0);
        ki2[t] = (float)(-sin(38.0 * th) / 256.0);
    }
}

// ---- circulant DFT matrices: KB[n][k] = f(n-k) ----
__global__ __launch_bounds__(256) void k_kmat(const float* __restrict__ kr2, const float* __restrict__ ki2,
    unsigned short* __restrict__ KBr, unsigned short* __restrict__ KBi)
{
    const int n = blockIdx.x, k = threadIdx.x;
    const int d = (n - k) & 255;
    KBr[n * 256 + k] = bf16u(kr2[d]);
    KBi[n * 256 + k] = bf16u(ki2[d]);
}

// ---------------- MFMA DFT pass 1 (x-direction), fp32 input with inline bf16 cvt ----------------
__global__ __launch_bounds__(256, 2) void k_mdft1(const float* __restrict__ xp,
    const unsigned short* __restrict__ KBr, const unsigned short* __restrict__ KBi,
    unsigned short* __restrict__ TR, unsigned short* __restrict__ TI)
{
    const int tid = threadIdx.x, lane = tid & 63, wave = tid >> 6;
    const int img = blockIdx.x >> 2;
    const int mb = (blockIdx.x >> 1) & 1, nb = blockIdx.x & 1;
    const int M0 = mb * 128 + (wave >> 1) * 64;
    const int N0 = nb * 128 + (wave & 1) * 64;
    const int lrow = lane & 15, lk = lane >> 4;
    const float* Xb = xp + (size_t)img * HW;

    f4v aR[4][4], aI[4][4];
#pragma unroll
    for (int m = 0; m < 4; m++)
#pragma unroll
        for (int n = 0; n < 4; n++) { aR[m][n] = (f4v){0,0,0,0}; aI[m][n] = (f4v){0,0,0,0}; }

#pragma unroll 1
    for (int k0 = 0; k0 < 256; k0 += 32) {
        bf8v af[4];
#pragma unroll
        for (int m = 0; m < 4; m++) {
            const float* rp = Xb + (size_t)(M0 + m * 16 + lrow) * 256 + k0 + lk * 8;
            const float4 a0 = *(const float4*)rp;
            const float4 a1 = *(const float4*)(rp + 4);
            bf8v t;
            t[0] = (short)bf16u(a0.x); t[1] = (short)bf16u(a0.y);
            t[2] = (short)bf16u(a0.z); t[3] = (short)bf16u(a0.w);
            t[4] = (short)bf16u(a1.x); t[5] = (short)bf16u(a1.y);
            t[6] = (short)bf16u(a1.z); t[7] = (short)bf16u(a1.w);
            af[m] = t;
        }
#pragma unroll
        for (int n = 0; n < 4; n++) {
            const int xcol = N0 + n * 16 + lrow;
            const bf8v br = *(const bf8v*)(KBr + xcol * 256 + k0 + lk * 8);
            const bf8v bi = *(const bf8v*)(KBi + xcol * 256 + k0 + lk * 8);
#pragma unroll
            for (int m = 0; m < 4; m++) {
                aR[m][n] = __builtin_amdgcn_mfma_f32_16x16x32_bf16(af[m], br, aR[m][n], 0, 0, 0);
                aI[m][n] = __builtin_amdgcn_mfma_f32_16x16x32_bf16(af[m], bi, aI[m][n], 0, 0, 0);
            }
        }
    }
#pragma unroll
    for (int n = 0; n < 4; n++) {
        const size_t xoff = (size_t)img * HW + (size_t)(N0 + n * 16 + lrow) * 256;
#pragma unroll
        for (int m = 0; m < 4; m++) {
            const size_t off = xoff + M0 + m * 16 + lk * 4;
            const f4v r = aR[m][n], ii = aI[m][n];
            ushort4 ur, ui;
            ur.x = bf16u(r[0]); ur.y = bf16u(r[1]); ur.z = bf16u(r[2]); ur.w = bf16u(r[3]);
            ui.x = bf16u(ii[0]); ui.y = bf16u(ii[1]); ui.z = bf16u(ii[2]); ui.w = bf16u(ii[3]);
            *(ushort4*)(TR + off) = ur;
            *(ushort4*)(TI + off) = ui;
        }
    }
}

// ---------------- MFMA DFT pass 2 (y-direction) ----------------
__global__ __launch_bounds__(256, 2) void k_mdft2(const unsigned short* __restrict__ TR,
    const unsigned short* __restrict__ TI, const unsigned short* __restrict__ KBr,
    const unsigned short* __restrict__ KBi, float* __restrict__ low)
{
    const int tid = threadIdx.x, lane = tid & 63, wave = tid >> 6;
    const int img = blockIdx.x >> 2;
    const int mb = (blockIdx.x >> 1) & 1, nb = blockIdx.x & 1;
    const int M0 = mb * 128 + (wave >> 1) * 64;
    const int N0 = nb * 128 + (wave & 1) * 64;
    const int lrow = lane & 15, lk = lane >> 4;
    const unsigned short* TRb = TR + (size_t)img * HW;
    const unsigned short* TIb = TI + (size_t)img * HW;

    f4v aR[4][4], aI[4][4];
#pragma unroll
    for (int m = 0; m < 4; m++)
#pragma unroll
        for (int n = 0; n < 4; n++) { aR[m][n] = (f4v){0,0,0,0}; aI[m][n] = (f4v){0,0,0,0}; }

#pragma unroll 1
    for (int k0 = 0; k0 < 256; k0 += 32) {
        bf8v afR[4], afI[4];
#pragma unroll
        for (int m = 0; m < 4; m++) {
            const int ro = (M0 + m * 16 + lrow) * 256 + k0 + lk * 8;
            afR[m] = *(const bf8v*)(TRb + ro);
            afI[m] = *(const bf8v*)(TIb + ro);
        }
#pragma unroll
        for (int n = 0; n < 4; n++) {
            const int ycol = N0 + n * 16 + lrow;
            const bf8v br = *(const bf8v*)(KBr + ycol * 256 + k0 + lk * 8);
            const bf8v bi = *(const bf8v*)(KBi + ycol * 256 + k0 + lk * 8);
#pragma unroll
            for (int m = 0; m < 4; m++) {
                aR[m][n] = __builtin_amdgcn_mfma_f32_16x16x32_bf16(afR[m], br, aR[m][n], 0, 0, 0);
                aI[m][n] = __builtin_amdgcn_mfma_f32_16x16x32_bf16(afI[m], bi, aI[m][n], 0, 0, 0);
            }
        }
    }
#pragma unroll
    for (int n = 0; n < 4; n++) {
        const size_t yoff = (size_t)img * HW + (size_t)(N0 + n * 16 + lrow) * 256;
#pragma unroll
        for (int m = 0; m < 4; m++) {
            const f4v r = aR[m][n], ii = aI[m][n];
            const float4 v = make_float4(r[0] - ii[0], r[1] - ii[1], r[2] - ii[2], r[3] - ii[3]);
            *(float4*)(low + yoff + M0 + m * 16 + lk * 4) = v;
        }
    }
}

// ---- W_eff = collapse(grouped 3x3, 1x1) -> bf16 [chunk][pos][oc][ch] ----
__global__ __launch_bounds__(256) void k_weff_bf(const float* __restrict__ w_u1,
    const float* __restrict__ w_con, unsigned short* __restrict__ wbf)
{
    const int f = blockIdx.x * 256 + threadIdx.x;
    if (f >= 73728) return;
    const int ch = f & 31, oc = (f >> 5) & 63, cp = f >> 11;
    const int pos = cp % 9, cb = cp / 9;
    const int g = cb * 32 + ch;
    float s = 0.f;
#pragma unroll
    for (int j = 0; j < 4; j++) s += w_u1[oc * 512 + g * 4 + j] * w_con[(g * 4 + j) * 9 + pos];
    wbf[f] = bf16u(s);
}

// ---- fp32 OIHW 3x3 weights -> bf16 [chunk][pos][oc][ch] ----
template<int CIN>
__global__ __launch_bounds__(256) void k_wcvt(const float* __restrict__ w, unsigned short* __restrict__ wbf)
{
    const int f = blockIdx.x * 256 + threadIdx.x;
    if (f >= 64 * CIN * 9) return;
    const int ch = f & 31, oc = (f >> 5) & 63, cp = f >> 11;
    const int pos = cp % 9, cb = cp / 9;
    const int c = cb * 32 + ch;
    wbf[f] = bf16u(w[oc * CIN * 9 + c * 9 + pos]);
}

// ---- fp32 1x1 weights [oc][CIN] -> bf16 [cb][oc][32ch] ----
template<int CIN>
__global__ __launch_bounds__(256) void k_wcvt1(const float* __restrict__ w, unsigned short* __restrict__ wbf)
{
    const int f = blockIdx.x * 256 + threadIdx.x;   // 64*CIN
    if (f >= 64 * CIN) return;
    const int ch = f & 31, oc = (f >> 5) & 63, cb = f >> 11;
    wbf[f] = bf16u(w[oc * CIN + cb * 32 + ch]);
}

// ---------------- MFMA 3x3 conv with fused norm-on-load + stats-on-store ----------------
// 256-px x 2-row block (FETCH ~131 MB), 512 thr / 8 waves (4/SIMD).
// R15: R14's (4px x 8ch) staging kept 32 floats live -> spilled past the (512,4)
// 128-reg budget (WRITE 67->95 MB). Split into two 4-ch halves (16 live floats,
// unroll 1): float4 loads retained, uint2 LDS writes, no spill.
template<int CIN>
__global__ __launch_bounds__(512, 4) void k_mconv(
    const float* __restrict__ in0, const float* __restrict__ in1,
    const unsigned short* __restrict__ wbf, const float* __restrict__ bias,
    float* __restrict__ out,
    const float* __restrict__ stA, const float* __restrict__ stB,
    float* __restrict__ psOut)
{
    __shared__ unsigned short Xl[4 * 260 * 32];   // row stride 16640 B
    __shared__ float sh_ms[2 * CIN];
    __shared__ float red[8][64][2];
    const int tid = threadIdx.x;
    const int lane = tid & 63;
    const int wave = tid >> 6;                 // 0..7
    const int b = blockIdx.x >> 7;
    const int y0 = (blockIdx.x & 127) * 2;
    const int row_sel = wave & 1;              // output row within pair
    const int px_base = (wave >> 1) * 64;      // px quarter
    const int split = blockIdx.x & (NSPLIT - 1);

    for (int i = tid; i < 4 * 260 * 32 / 2; i += 512) ((unsigned int*)Xl)[i] = 0u;
    for (int j = tid; j < 2 * CIN; j += 512) {
        const int cg = j >> 1;
        const float* st = (CIN == 128 && cg >= 64) ? stB : stA;
        sh_ms[j] = st[(b * 64 + (cg & 63)) * 2 + (j & 1)];
    }

    f4v acc[4][4];
#pragma unroll
    for (int i = 0; i < 4; i++)
#pragma unroll
        for (int n = 0; n < 4; n++) acc[i][n] = (f4v){0.f, 0.f, 0.f, 0.f};

    const int lrow = lane & 15;
    const int gsl  = lane >> 4;
    const int wlane = lrow * 32 + gsl * 8;

    __syncthreads();    // init + sh_ms visible

    constexpr int NC = CIN / 32;
#pragma unroll 1
    for (int cb = 0; cb < NC; cb++) {
        const int c0 = cb * 32;
        const bool second = (CIN == 128 && c0 >= 64);
        const float* src = (second ? in1 : in0) + ((size_t)b * 64 + (c0 & 63)) * HW;
        const float* ms = sh_ms + cb * 64;
        {   // stage 4 rows x 256 px x 32 ch: thread = (px quad, 8-ch group, row pair),
            // processed in two 4-ch halves to bound live regs (R14 spill lesson)
            const int q   = tid & 63;
            const int g   = (tid >> 6) & 3;
            const int rg  = tid >> 8;
            const int px0 = q * 4;
#pragma unroll
            for (int r2 = 0; r2 < 2; r2++) {
                const int r = rg * 2 + r2;
                const int yy = y0 - 1 + r;
                if (yy < 0 || yy > 255) continue;
                const float* rp = src + (size_t)(g * 8) * HW + (size_t)yy * WIDTH + px0;
#pragma unroll 1
                for (int h = 0; h < 2; h++) {
                    float v[4][4];
#pragma unroll
                    for (int cc = 0; cc < 4; cc++) {
                        const float4 ld = *(const float4*)(rp + (size_t)(h * 4 + cc) * HW);
                        const float mm  = ms[(g * 8 + h * 4 + cc) * 2];
                        const float ssv = ms[(g * 8 + h * 4 + cc) * 2 + 1];
                        v[cc][0] = lrelu_f((ld.x - mm) * ssv);
                        v[cc][1] = lrelu_f((ld.y - mm) * ssv);
                        v[cc][2] = lrelu_f((ld.z - mm) * ssv);
                        v[cc][3] = lrelu_f((ld.w - mm) * ssv);
                    }
#pragma unroll
                    for (int p = 0; p < 4; p++) {
                        const int slot = px0 + p + 1;
                        const int sw = (slot >> 1) & 3;
                        uint2 w2;
                        w2.x = (unsigned)bf16u(v[0][p]) | ((unsigned)bf16u(v[1][p]) << 16);
                        w2.y = (unsigned)bf16u(v[2][p]) | ((unsigned)bf16u(v[3][p]) << 16);
                        *(uint2*)((char*)Xl + r * 16640 + slot * 64
                                  + ((g ^ sw) << 4) + h * 8) = w2;
                    }
                }
            }
        }
        __syncthreads();
#pragma unroll 1
        for (int pos = 0; pos < 9; pos++) {
            const int dy = pos / 3, dx = pos - dy * 3;
            const unsigned short* wp = wbf + (cb * 9 + pos) * 2048 + wlane;
            const bf8v wf0 = *(const bf8v*)(wp);
            const bf8v wf1 = *(const bf8v*)(wp + 512);
            const bf8v wf2 = *(const bf8v*)(wp + 1024);
            const bf8v wf3 = *(const bf8v*)(wp + 1536);
            const int pxe = px_base + lrow + dx;           // slot = px+1 with dx-1 offset
            const int row = row_sel + dy;
            const char* abase = (const char*)Xl + row * 16640 + pxe * 64
                              + ((gsl ^ ((pxe >> 1) & 3)) << 4);
#pragma unroll
            for (int i = 0; i < 4; i++) {
                const bf8v af = *(const bf8v*)(abase + i * 1024);   // +16 px: swizzle invariant
                acc[i][0] = __builtin_amdgcn_mfma_f32_16x16x32_bf16(af, wf0, acc[i][0], 0, 0, 0);
                acc[i][1] = __builtin_amdgcn_mfma_f32_16x16x32_bf16(af, wf1, acc[i][1], 0, 0, 0);
                acc[i][2] = __builtin_amdgcn_mfma_f32_16x16x32_bf16(af, wf2, acc[i][2], 0, 0, 0);
                acc[i][3] = __builtin_amdgcn_mfma_f32_16x16x32_bf16(af, wf3, acc[i][3], 0, 0, 0);
            }
        }
        __syncthreads();
    }
    // epilogue: store + per-oc stats
    const int yrow = y0 + row_sel;
    const int lk = gsl;
#pragma unroll
    for (int n = 0; n < 4; n++) {
        const float bv = bias[n * 16 + lrow];
        float* po = out + ((size_t)(b * 64) + n * 16 + lrow) * HW
                  + (size_t)yrow * WIDTH + px_base + lk * 4;
        float s = 0.f, s2 = 0.f;
#pragma unroll
        for (int i = 0; i < 4; i++) {
            const f4v a = acc[i][n];
            float4 v;
            v.x = a[0] + bv; v.y = a[1] + bv; v.z = a[2] + bv; v.w = a[3] + bv;
            s  += v.x + v.y + v.z + v.w;
            s2 += v.x*v.x + v.y*v.y + v.z*v.z + v.w*v.w;
            *(float4*)(po + i * 16) = v;
        }
        s  += __shfl_down(s, 32);  s  += __shfl_down(s, 16);
        s2 += __shfl_down(s2, 32); s2 += __shfl_down(s2, 16);
        if (lk == 0) { red[wave][n * 16 + lrow][0] = s; red[wave][n * 16 + lrow][1] = s2; }
    }
    __syncthreads();
    if (tid < 64) {
        float S = 0.f, S2 = 0.f;
#pragma unroll
        for (int w = 0; w < 8; w++) { S += red[w][tid][0]; S2 += red[w][tid][1]; }
        float* pp = &psOut[((b * 64 + tid) * NSPLIT + split) * 2];
        atomicAdd(pp, S);
        atomicAdd(pp + 1, S2);
    }
}

// ---------------- MFMA pointwise (1x1) conv ----------------
// R14: staging (4px x 8ch)/thread: 8 float4 loads + 4 uint4 LDS writes per chunk.
// (256,3) reg cap ~168 absorbs the 32-float buffer — no spill here.
template<int CIN, bool ADD, bool NORMIN, bool STATS>
__global__ __launch_bounds__(256, 3) void k_pconv(
    const float* __restrict__ in0, const float* __restrict__ in1,
    const unsigned short* __restrict__ wbf, const float* __restrict__ bias,
    const float* __restrict__ addsrc, float* __restrict__ out,
    const float* __restrict__ stA, const float* __restrict__ stB,
    const float* __restrict__ stAdd, float* __restrict__ psOut)
{
    __shared__ unsigned short Xl[256 * 32];      // [px][32ch], 16B-slot swizzled
    __shared__ float sh_ms[2 * CIN];
    __shared__ float red[4][64][2];
    const int tid = threadIdx.x, lane = tid & 63, wave = tid >> 6;
    const int y = blockIdx.x & 255, b = blockIdx.x >> 8;
    const int split = blockIdx.x & (NSPLIT - 1);
    const int lrow = lane & 15, gsl = lane >> 4;
    const int wpx = wave * 64;
    const int wlane = lrow * 32 + gsl * 8;

    if constexpr (NORMIN) {
        for (int j = tid; j < 2 * CIN; j += 256) {
            const int cg = j >> 1;
            const float* st = (CIN == 128 && cg >= 64) ? stB : stA;
            sh_ms[j] = st[(b * 64 + (cg & 63)) * 2 + (j & 1)];
        }
    }

    f4v acc[4][4];
#pragma unroll
    for (int m = 0; m < 4; m++)
#pragma unroll
        for (int n = 0; n < 4; n++) acc[m][n] = (f4v){0.f, 0.f, 0.f, 0.f};

    __syncthreads();

    constexpr int NC = CIN / 32;
#pragma unroll 1
    for (int cb = 0; cb < NC; cb++) {
        const int c0 = cb * 32;
        const bool second = (CIN == 128 && c0 >= 64);
        const float* src = (second ? in1 : in0) + ((size_t)b * 64 + (c0 & 63)) * HW
                         + (size_t)y * WIDTH;
        const float* ms = sh_ms + cb * 64;
        {   // stage 256 px x 32 ch: thread = (px quad, 8-ch group)
            const int q = tid & 63, g = tid >> 6;
            const int px0 = q * 4;
            const float* rp = src + (size_t)(g * 8) * HW + px0;
            float v[8][4];
#pragma unroll
            for (int cc = 0; cc < 8; cc++) {
                const float4 ld = *(const float4*)(rp + (size_t)cc * HW);
                if constexpr (NORMIN) {
                    const float mm  = ms[(g * 8 + cc) * 2];
                    const float ssv = ms[(g * 8 + cc) * 2 + 1];
                    v[cc][0] = lrelu_f((ld.x - mm) * ssv);
                    v[cc][1] = lrelu_f((ld.y - mm) * ssv);
                    v[cc][2] = lrelu_f((ld.z - mm) * ssv);
                    v[cc][3] = lrelu_f((ld.w - mm) * ssv);
                } else {
                    v[cc][0] = ld.x; v[cc][1] = ld.y; v[cc][2] = ld.z; v[cc][3] = ld.w;
                }
            }
#pragma unroll
            for (int p = 0; p < 4; p++) {
                const int px = px0 + p;
                const int sw = (px >> 1) & 3;
                uint4 w4;
                w4.x = (unsigned)bf16u(v[0][p]) | ((unsigned)bf16u(v[1][p]) << 16);
                w4.y = (unsigned)bf16u(v[2][p]) | ((unsigned)bf16u(v[3][p]) << 16);
                w4.z = (unsigned)bf16u(v[4][p]) | ((unsigned)bf16u(v[5][p]) << 16);
                w4.w = (unsigned)bf16u(v[6][p]) | ((unsigned)bf16u(v[7][p]) << 16);
                *(uint4*)((char*)Xl + px * 64 + ((g ^ sw) << 4)) = w4;
            }
        }
        __syncthreads();
        {
            const unsigned short* wp = wbf + cb * 2048 + wlane;
            const bf8v wf0 = *(const bf8v*)(wp);
            const bf8v wf1 = *(const bf8v*)(wp + 512);
            const bf8v wf2 = *(const bf8v*)(wp + 1024);
            const bf8v wf3 = *(const bf8v*)(wp + 1536);
#pragma unroll
            for (int m = 0; m < 4; m++) {
                const int px = wpx + m * 16 + lrow;
                const char* abase = (const char*)Xl + px * 64
                                  + ((gsl ^ ((px >> 1) & 3)) << 4);
                const bf8v af = *(const bf8v*)abase;
                acc[m][0] = __builtin_amdgcn_mfma_f32_16x16x32_bf16(af, wf0, acc[m][0], 0, 0, 0);
                acc[m][1] = __builtin_amdgcn_mfma_f32_16x16x32_bf16(af, wf1, acc[m][1], 0, 0, 0);
                acc[m][2] = __builtin_amdgcn_mfma_f32_16x16x32_bf16(af, wf2, acc[m][2], 0, 0, 0);
                acc[m][3] = __builtin_amdgcn_mfma_f32_16x16x32_bf16(af, wf3, acc[m][3], 0, 0, 0);
            }
        }
        __syncthreads();
    }
    // epilogue: bias (+ normed residual) + store (+ stats)
    const int lk = gsl;
#pragma unroll
    for (int n = 0; n < 4; n++) {
        const int oc = n * 16 + lrow;
        const float bv = bias[oc];
        float mm = 0.f, ss = 0.f;
        if constexpr (ADD) { mm = stAdd[(b * 64 + oc) * 2]; ss = stAdd[(b * 64 + oc) * 2 + 1]; }
        const size_t orow = ((size_t)(b * 64 + oc)) * HW + (size_t)y * WIDTH;
        float s = 0.f, s2 = 0.f;
#pragma unroll
        for (int m = 0; m < 4; m++) {
            const int px = wpx + m * 16 + lk * 4;
            const f4v a = acc[m][n];
            float r[4] = { a[0] + bv, a[1] + bv, a[2] + bv, a[3] + bv };
            if constexpr (ADD) {
                const float4 av = *(const float4*)(addsrc + orow + px);
                r[0] += lrelu_f((av.x - mm) * ss);
                r[1] += lrelu_f((av.y - mm) * ss);
                r[2] += lrelu_f((av.z - mm) * ss);
                r[3] += lrelu_f((av.w - mm) * ss);
            }
            *(float4*)(out + orow + px) = make_float4(r[0], r[1], r[2], r[3]);
            if constexpr (STATS) {
                s  += r[0] + r[1] + r[2] + r[3];
                s2 += r[0]*r[0] + r[1]*r[1] + r[2]*r[2] + r[3]*r[3];
            }
        }
        if constexpr (STATS) {
            s  += __shfl_down(s, 32);  s  += __shfl_down(s, 16);
            s2 += __shfl_down(s2, 32); s2 += __shfl_down(s2, 16);
            if (lk == 0) { red[wave][oc][0] = s; red[wave][oc][1] = s2; }
        }
    }
    if constexpr (STATS) {
        __syncthreads();
        if (tid < 64) {
            const float S  = red[0][tid][0] + red[1][tid][0] + red[2][tid][0] + red[3][tid][0];
            const float S2 = red[0][tid][1] + red[1][tid][1] + red[2][tid][1] + red[3][tid][1];
            float* pp = &psOut[((b * 64 + tid) * NSPLIT + split) * 2];
            atomicAdd(pp, S);
            atomicAdd(pp + 1, S2);
        }
    }
}

// ---------------- 2x2 max pool ----------------
__global__ __launch_bounds__(256) void k_maxpool(const float* __restrict__ feat, float* __restrict__ out)
{
    const int idx = blockIdx.x * 256 + threadIdx.x;
    const int xo = idx & 127;
    const int yo = (idx >> 7) & 127;
    const int img = idx >> 14;
    const float* p = feat + (size_t)img * HW + (size_t)(yo * 2) * WIDTH + xo * 2;
    out[idx] = fmaxf(fmaxf(p[0], p[1]), fmaxf(p[WIDTH], p[WIDTH + 1]));
}

extern "C" void kernel_launch(void* const* d_in, const int* in_sizes, int n_in,
                              void* d_out, int out_size, void* d_ws, size_t ws_size,
                              hipStream_t stream)
{
    const float* x      = (const float*)d_in[0];
    const float* w_proj = (const float*)d_in[1];
    const float* b_proj = (const float*)d_in[2];
    const float* w_a1   = (const float*)d_in[3];
    const float* w_a2   = (const float*)d_in[4];
    const float* w_ref  = (const float*)d_in[5];
    const float* b_ref  = (const float*)d_in[6];
    const float* w_fuse = (const float*)d_in[7];
    const float* b_fuse = (const float*)d_in[8];
    const float* w_con  = (const float*)d_in[9];
    const float* w_u1   = (const float*)d_in[10];
    const float* b_u1   = (const float*)d_in[11];
    const float* w_u2   = (const float*)d_in[12];
    const float* b_u2   = (const float*)d_in[13];
    const float* w_sc   = (const float*)d_in[14];
    const float* b_sc   = (const float*)d_in[15];

    float* wsf  = (float*)d_ws;
    float* buf0 = wsf;                       // xp -> fuse_raw
    float* buf1 = wsf + (size_t)IMG;         // xw raw
    float* buf2 = wsf + (size_t)2 * IMG;     // T1R/T1I bf16 overlay -> u2raw
    float* aux  = wsf + (size_t)3 * IMG;
    float* a2b  = aux;                       // 256
    float* kr2  = aux + 256;                 // 512
    float* ki2  = aux + 768;                 // 512
    unsigned short* wbfA = (unsigned short*)(aux + 1280);    // 73728 ushort
    unsigned short* wbfB = wbfA + 73728;                     // 36864 ushort
    unsigned short* KBr  = wbfB + 36864;                     // 65536 ushort
    unsigned short* KBi  = KBr + 65536;                      // 65536 ushort
    unsigned short* wbfF = KBi + 65536;                      // 4096 ushort (fuse 1x1)
    unsigned short* wbfS = wbfF + 4096;                      // 8192 ushort (sc 1x1)
    float* ps   = aux + 1280 + 120832 + 6144;  // 5 slots x 256 imgs x NSPLIT x 2
    float* st   = ps + 5 * 256 * NSPLIT * 2;   // 5 slots x 256 x 2

    float* fout = (float*)d_out;             // low -> u1raw -> feat
    float* pout = fout + (size_t)IMG;        // pooled
    unsigned short* T1R = (unsigned short*)buf2;
    unsigned short* T1I = T1R + (size_t)IMG;

    const int PSSLOT = 256 * NSPLIT * 2;     // 8192 floats per slot

    hipMemsetAsync(ps, 0, 5 * PSSLOT * sizeof(float), stream);
    k_tables<<<2, 256, 0, stream>>>(kr2, ki2);
    k_kmat<<<256, 256, 0, stream>>>(kr2, ki2, KBr, KBi);
    k_weff_bf<<<288, 256, 0, stream>>>(w_u1, w_con, wbfA);
    k_wcvt<64><<<144, 256, 0, stream>>>(w_u2, wbfB);
    k_wcvt1<64><<<16, 256, 0, stream>>>(w_fuse, wbfF);
    k_wcvt1<128><<<32, 256, 0, stream>>>(w_sc, wbfS);
    k_proj<<<2048, 256, 0, stream>>>(x, w_proj, b_proj, buf0, ps);
    k_attention<<<1, 256, 0, stream>>>(ps, w_a1, w_a2, a2b);
    k_dw<<<16384, 256, 0, stream>>>(buf0, a2b, w_ref, b_ref, buf1, ps + PSSLOT);
    k_mdft1<<<1024, 256, 0, stream>>>(buf0, KBr, KBi, T1R, T1I);
    k_mdft2<<<1024, 256, 0, stream>>>(T1R, T1I, KBr, KBi, fout);
    k_pconv<64, false, false, true><<<1024, 256, 0, stream>>>(
        fout, nullptr, wbfF, b_fuse, nullptr, buf0,
        nullptr, nullptr, nullptr, ps + 2 * PSSLOT);
    k_statsf<<<2, 256, 0, stream>>>(ps + PSSLOT, st + 512);       // st1 (dw), st2 (fuse)
    k_mconv<128><<<512, 512, 0, stream>>>(buf1, buf0, wbfA, b_u1, fout,
        st + 512, st + 1024, ps + 3 * PSSLOT);
    k_statsf<<<1, 256, 0, stream>>>(ps + 3 * PSSLOT, st + 1536);  // st3
    k_mconv<64><<<512, 512, 0, stream>>>(fout, nullptr, wbfB, b_u2, buf2,
        st + 1536, st + 1536, ps + 4 * PSSLOT);
    k_statsf<<<1, 256, 0, stream>>>(ps + 4 * PSSLOT, st + 2048);  // st4
    k_pconv<128, true, true, false><<<1024, 256, 0, stream>>>(
        buf1, buf0, wbfS, b_sc, buf2, fout,
        st + 512, st + 1024, st + 2048, nullptr);
    k_maxpool<<<16384, 256, 0, stream>>>(fout, pout);
}